// Round 19
// baseline (76.693 us; speedup 1.0000x reference)
//
#include <hip/hip_runtime.h>
#include <hip/hip_bf16.h>
#include <stdint.h>
#include <stddef.h>

#define GN 6144
#define GH 4
#define HALF 3072
#define MAXD2 256  /* slots per HALF-row; deg/2 ~ 154 +/- 12 (8.5 sigma) */

typedef float    f32x2  __attribute__((ext_vector_type(2)));
typedef float    f32x4  __attribute__((ext_vector_type(4)));
typedef float    f32x16 __attribute__((ext_vector_type(16)));
typedef unsigned u32x4  __attribute__((ext_vector_type(4)));
typedef __bf16   bf16x4 __attribute__((ext_vector_type(4)));
typedef __bf16   bf16x8 __attribute__((ext_vector_type(8)));

__device__ __forceinline__ float fast_exp2(float x) {
#if __has_builtin(__builtin_amdgcn_exp2f)
  return __builtin_amdgcn_exp2f(x);
#else
  return exp2f(x);
#endif
}

// ---------------- K1: wh GEMM -> row-major bf16 whR + lp2/lc2 ------------
__global__ __launch_bounds__(256) void gat_wh(const float* __restrict__ hm,
                                              const float* __restrict__ wgt,
                                              const float* __restrict__ aw,
                                              __bf16* __restrict__ whR,
                                              float* __restrict__ lp2,
                                              float* __restrict__ lc2) {
  __shared__ float ldsC[64 * 132];
  const int t = threadIdx.x;
  const int wave = t >> 6, lane = t & 63;
  const int col = lane & 31, kg = lane >> 5;
  const int n0 = blockIdx.x * 64;
  const int rowHalf = (wave & 1) * 32;
  const int colBase = (wave >> 1) * 64;

  f32x16 acc[2];
#pragma unroll
  for (int ct = 0; ct < 2; ++ct)
#pragma unroll
    for (int i = 0; i < 16; ++i) acc[ct][i] = 0.0f;

#pragma unroll
  for (int kk = 0; kk < 8; ++kk) {
    const int k = kk * 16 + kg * 8;
    const f32x4 h0 = *(const f32x4*)(hm + (size_t)(n0 + rowHalf + col) * 128 + k);
    const f32x4 h1 = *(const f32x4*)(hm + (size_t)(n0 + rowHalf + col) * 128 + k + 4);
    bf16x8 af;
#pragma unroll
    for (int e = 0; e < 4; ++e) { af[e] = (__bf16)h0[e]; af[e + 4] = (__bf16)h1[e]; }
#pragma unroll
    for (int ct = 0; ct < 2; ++ct) {
      bf16x8 bfr;  // wgt column reads: coalesced across lanes
#pragma unroll
      for (int e = 0; e < 8; ++e)
        bfr[e] = (__bf16)wgt[(size_t)(k + e) * 128 + colBase + ct * 32 + col];
      acc[ct] = __builtin_amdgcn_mfma_f32_32x32x16_bf16(af, bfr, acc[ct], 0, 0, 0);
    }
  }
  // C layout (32x32): col = lane&31, row = (r&3) + 8*(r>>2) + 4*(lane>>5)
#pragma unroll
  for (int ct = 0; ct < 2; ++ct)
#pragma unroll
    for (int r = 0; r < 16; ++r)
      ldsC[(rowHalf + (r & 3) + 8 * (r >> 2) + 4 * kg) * 132 + colBase + ct * 32 + col] =
          acc[ct][r];
  __syncthreads();

  {  // ROW-MAJOR bf16 store: whR[n][f] (sparse PV gathers whole rows)
    const int rr = t >> 2, cg = (t & 3) * 32;
    __bf16* dst = whR + (size_t)(n0 + rr) * 128 + cg;
#pragma unroll
    for (int q = 0; q < 4; ++q) {
      bf16x8 v;
#pragma unroll
      for (int e = 0; e < 8; ++e) v[e] = (__bf16)ldsC[rr * 132 + cg + q * 8 + e];
      *(bf16x8*)(dst + q * 8) = v;
    }
  }
  {  // lp/lc dots, pre-scaled by log2(e)
    const int nl = t & 63, h = t >> 6;
    float sp = 0.f, sd = 0.f;
#pragma unroll
    for (int f = 0; f < 32; ++f) {
      const float v = ldsC[nl * 132 + h * 32 + f];
      sp = fmaf(v, aw[h * 64 + f], sp);
      sd = fmaf(v, aw[h * 64 + 32 + f], sd);
    }
    const float LOG2E = 1.4426950408889634f;
    lp2[(n0 + nl) * GH + h] = sp * LOG2E;
    lc2[(n0 + nl) * GH + h] = sd * LOG2E;
  }
}

// ---------------- K2: FUSED, cross-task software-pipelined ---------------
// Each wave owns TWO half-row tasks. t1's adj-compact is interleaved into
// t0's PV loop (every 3rd group): t1's HBM/L3 streams ride under t0's
// FMA+L2-gather chain, breaking the chip-wide phase lockstep (R16-R18:
// phases summed; VALUBusy ~37% = VALU phase share). Grid 1536 = 6
// blocks/CU, fully resident, single batch, no tail.
__global__ __launch_bounds__(256) void gat_fused(const float* __restrict__ adj,
                                                 const __bf16* __restrict__ whR,
                                                 const float* __restrict__ lp2,
                                                 const float* __restrict__ lc2,
                                                 float* __restrict__ out) {
  __shared__ unsigned short jidx[4][2][MAXD2];  // 4 KB
  __shared__ __bf16 elsb[4][MAXD2 * GH];        // 8 KB (reused t0 -> t1)
  __shared__ float accx[4][16][8];              // 2 KB
  __shared__ float denx[4][4];                  // 64 B
  const int t = threadIdx.x, wave = t >> 6, lane = t & 63;
  const int r0 = blockIdx.x * 4 + (wave >> 1);  // task0 row
  const int r1 = r0 + 2;                        // task1 row
  const int half = wave & 1;
  const float* arow0 = adj + (size_t)r0 * GN + half * HALF;
  const float* arow1 = adj + (size_t)r1 * GN + half * HALF;
  const int qlane = lane & 15;         // feature group: feats qlane*8..+8
  const int elane = lane >> 4;         // edge slot within group of 4
  const int hsel = qlane >> 2;         // head of this lane's 8 feats

  // ================= P1(t0): ballot-compact, depth-4 prefetch ============
  unsigned base0 = 0;
  {
    f32x4 buf[4];
#pragma unroll
    for (int c = 0; c < 4; ++c) buf[c] = *(const f32x4*)(arow0 + c * 256 + lane * 4);
#pragma unroll 4
    for (int c = 0; c < 12; ++c) {    // c&3 static under unroll-4
      const f32x4 a = buf[c & 3];
      if (c + 4 < 12) buf[c & 3] = *(const f32x4*)(arow0 + (c + 4) * 256 + lane * 4);
#pragma unroll
      for (int s = 0; s < 4; ++s) {
        const bool p = a[s] > 0.f;
        const unsigned long long m = __ballot(p);
        const unsigned rank = (unsigned)__popcll(m & ((1ull << lane) - 1ull));
        const unsigned pos = base0 + rank;
        if (p && pos < MAXD2)
          jidx[wave][0][pos] = (unsigned short)(half * HALF + c * 256 + lane * 4 + s);
        base0 += (unsigned)__popcll(m);
      }
    }
  }
  int dg0 = (int)base0;  if (dg0 > MAXD2) dg0 = MAXD2;
  for (int k = dg0 + lane; k < MAXD2; k += 64) jidx[wave][0][k] = 0;

  const f32x4 lpv = *(const f32x4*)(lp2 + (size_t)r0 * GH);  // same for r1? NO
  // (lp differs per row; load separately below for t1)

  // ================= P2a(t0): e-phase, fixed 4 chunks (fills all elsb) ===
  f32x2 d01 = f32x2{0.f, 0.f}, d23 = f32x2{0.f, 0.f};
#pragma unroll
  for (int c = 0; c < 4; ++c) {
    const int k = c * 64 + lane;
    const bool valid = k < dg0;
    const int jv = valid ? (int)jidx[wave][0][k] : 0;
    const f32x4 lc = *(const f32x4*)(lc2 + (size_t)jv * GH);
    f32x2 x01 = f32x2{lpv[0] + lc[0], lpv[1] + lc[1]};
    f32x2 x23 = f32x2{lpv[2] + lc[2], lpv[3] + lc[3]};
    x01 = __builtin_elementwise_max(x01, x01 * 0.2f);
    x23 = __builtin_elementwise_max(x23, x23 * 0.2f);
    const float vf = valid ? 1.f : 0.f;
    const f32x2 e01 = f32x2{fast_exp2(x01[0]), fast_exp2(x01[1])} * vf;
    const f32x2 e23 = f32x2{fast_exp2(x23[0]), fast_exp2(x23[1])} * vf;
    d01 += e01; d23 += e23;
    bf16x4 ep;
    ep[0] = (__bf16)e01[0]; ep[1] = (__bf16)e01[1];
    ep[2] = (__bf16)e23[0]; ep[3] = (__bf16)e23[1];
    *(bf16x4*)&elsb[wave][k * 4] = ep;
  }

  // ================= PV(t0) fused with P1(t1) ============================
  unsigned base1 = 0;
  int c1 = 0, cd = 0;
  f32x4 bA = *(const f32x4*)(arow1 + 0 * 256 + lane * 4);
  f32x4 bB = *(const f32x4*)(arow1 + 1 * 256 + lane * 4);
  f32x4 bC = *(const f32x4*)(arow1 + 2 * 256 + lane * 4);
  f32x4 bD = *(const f32x4*)(arow1 + 3 * 256 + lane * 4);

#define T1_CHUNK()                                                             \
  do {                                                                         \
    const f32x4 a = bA;                                                        \
    _Pragma("unroll")                                                          \
    for (int s = 0; s < 4; ++s) {                                              \
      const bool p = a[s] > 0.f;                                               \
      const unsigned long long m = __ballot(p);                                \
      const unsigned rank = (unsigned)__popcll(m & ((1ull << lane) - 1ull));   \
      const unsigned pos = base1 + rank;                                       \
      if (p && pos < MAXD2)                                                    \
        jidx[wave][1][pos] =                                                   \
            (unsigned short)(half * HALF + c1 * 256 + lane * 4 + s);           \
      base1 += (unsigned)__popcll(m);                                          \
    }                                                                          \
    bA = bB; bB = bC; bC = bD;                                                 \
    if (c1 + 4 < 12) bD = *(const f32x4*)(arow1 + (c1 + 4) * 256 + lane * 4);  \
    ++c1;                                                                      \
  } while (0)

  f32x4 accA = f32x4{0.f, 0.f, 0.f, 0.f};
  f32x4 accB = f32x4{0.f, 0.f, 0.f, 0.f};
  {
    const int ngrp = (dg0 + 3) >> 2;
    for (int g = 0; g < ngrp; ++g) {
      if (cd == 0 && c1 < 12) { T1_CHUNK(); cd = 3; }
      --cd;
      const int es = g * 4 + elane;
      const int jj = (int)jidx[wave][0][es];
      const u32x4 wb = *(const u32x4*)(whR + (size_t)jj * 128 + qlane * 8);
      const float eb = (float)elsb[wave][es * 4 + hsel];
#pragma unroll
      for (int w = 0; w < 4; ++w) {
        const float wlo = __uint_as_float(wb[w] << 16);
        const float whi = __uint_as_float(wb[w] & 0xffff0000u);
        if (w < 2) {
          accA[2 * w]     = fmaf(eb, wlo, accA[2 * w]);
          accA[2 * w + 1] = fmaf(eb, whi, accA[2 * w + 1]);
        } else {
          accB[2 * w - 4] = fmaf(eb, wlo, accB[2 * w - 4]);
          accB[2 * w - 3] = fmaf(eb, whi, accB[2 * w - 3]);
        }
      }
    }
    while (c1 < 12) T1_CHUNK();       // cleanup (short ngrp)
  }
  int dg1 = (int)base1;  if (dg1 > MAXD2) dg1 = MAXD2;
  for (int k = dg1 + lane; k < MAXD2; k += 64) jidx[wave][1][k] = 0;

  // ================= combine + store t0 ==================================
#pragma unroll
  for (int off = 16; off <= 32; off <<= 1)
#pragma unroll
    for (int e = 0; e < 4; ++e) {
      accA[e] += __shfl_xor(accA[e], off);
      accB[e] += __shfl_xor(accB[e], off);
    }
  f32x4 dv = f32x4{d01[0], d01[1], d23[0], d23[1]};
#pragma unroll
  for (int off = 1; off < 64; off <<= 1) {
    dv[0] += __shfl_xor(dv[0], off);
    dv[1] += __shfl_xor(dv[1], off);
    dv[2] += __shfl_xor(dv[2], off);
    dv[3] += __shfl_xor(dv[3], off);
  }
  if (lane < 16) {
    *(f32x4*)&accx[wave][qlane][0] = accA;
    *(f32x4*)&accx[wave][qlane][4] = accB;
  }
  if (lane == 0) *(f32x4*)&denx[wave][0] = dv;
  __syncthreads();
  if ((wave & 1) == 0 && lane < 16) {
    const f32x4 pA = *(const f32x4*)&accx[wave + 1][qlane][0];
    const f32x4 pB = *(const f32x4*)&accx[wave + 1][qlane][4];
    const float den = denx[wave][hsel] + denx[wave + 1][hsel];
    const float inv = 1.0f / den;
    *(f32x4*)(out + (size_t)r0 * 128 + qlane * 8)     = (accA + pA) * inv;
    *(f32x4*)(out + (size_t)r0 * 128 + qlane * 8 + 4) = (accB + pB) * inv;
  }
  __syncthreads();                     // protect accx/denx reuse

  // ================= P2a(t1) + PV(t1) ====================================
  const f32x4 lpv1 = *(const f32x4*)(lp2 + (size_t)r1 * GH);
  d01 = f32x2{0.f, 0.f}; d23 = f32x2{0.f, 0.f};
#pragma unroll
  for (int c = 0; c < 4; ++c) {
    const int k = c * 64 + lane;
    const bool valid = k < dg1;
    const int jv = valid ? (int)jidx[wave][1][k] : 0;
    const f32x4 lc = *(const f32x4*)(lc2 + (size_t)jv * GH);
    f32x2 x01 = f32x2{lpv1[0] + lc[0], lpv1[1] + lc[1]};
    f32x2 x23 = f32x2{lpv1[2] + lc[2], lpv1[3] + lc[3]};
    x01 = __builtin_elementwise_max(x01, x01 * 0.2f);
    x23 = __builtin_elementwise_max(x23, x23 * 0.2f);
    const float vf = valid ? 1.f : 0.f;
    const f32x2 e01 = f32x2{fast_exp2(x01[0]), fast_exp2(x01[1])} * vf;
    const f32x2 e23 = f32x2{fast_exp2(x23[0]), fast_exp2(x23[1])} * vf;
    d01 += e01; d23 += e23;
    bf16x4 ep;
    ep[0] = (__bf16)e01[0]; ep[1] = (__bf16)e01[1];
    ep[2] = (__bf16)e23[0]; ep[3] = (__bf16)e23[1];
    *(bf16x4*)&elsb[wave][k * 4] = ep;
  }
  accA = f32x4{0.f, 0.f, 0.f, 0.f};
  accB = f32x4{0.f, 0.f, 0.f, 0.f};
  {
    const int ngrp = (dg1 + 3) >> 2;
#pragma unroll 4
    for (int g = 0; g < ngrp; ++g) {
      const int es = g * 4 + elane;
      const int jj = (int)jidx[wave][1][es];
      const u32x4 wb = *(const u32x4*)(whR + (size_t)jj * 128 + qlane * 8);
      const float eb = (float)elsb[wave][es * 4 + hsel];
#pragma unroll
      for (int w = 0; w < 4; ++w) {
        const float wlo = __uint_as_float(wb[w] << 16);
        const float whi = __uint_as_float(wb[w] & 0xffff0000u);
        if (w < 2) {
          accA[2 * w]     = fmaf(eb, wlo, accA[2 * w]);
          accA[2 * w + 1] = fmaf(eb, whi, accA[2 * w + 1]);
        } else {
          accB[2 * w - 4] = fmaf(eb, wlo, accB[2 * w - 4]);
          accB[2 * w - 3] = fmaf(eb, whi, accB[2 * w - 3]);
        }
      }
    }
  }
#pragma unroll
  for (int off = 16; off <= 32; off <<= 1)
#pragma unroll
    for (int e = 0; e < 4; ++e) {
      accA[e] += __shfl_xor(accA[e], off);
      accB[e] += __shfl_xor(accB[e], off);
    }
  dv = f32x4{d01[0], d01[1], d23[0], d23[1]};
#pragma unroll
  for (int off = 1; off < 64; off <<= 1) {
    dv[0] += __shfl_xor(dv[0], off);
    dv[1] += __shfl_xor(dv[1], off);
    dv[2] += __shfl_xor(dv[2], off);
    dv[3] += __shfl_xor(dv[3], off);
  }
  if (lane < 16) {
    *(f32x4*)&accx[wave][qlane][0] = accA;
    *(f32x4*)&accx[wave][qlane][4] = accB;
  }
  if (lane == 0) *(f32x4*)&denx[wave][0] = dv;
  __syncthreads();
  if ((wave & 1) == 0 && lane < 16) {
    const f32x4 pA = *(const f32x4*)&accx[wave + 1][qlane][0];
    const f32x4 pB = *(const f32x4*)&accx[wave + 1][qlane][4];
    const float den = denx[wave][hsel] + denx[wave + 1][hsel];
    const float inv = 1.0f / den;
    *(f32x4*)(out + (size_t)r1 * 128 + qlane * 8)     = (accA + pA) * inv;
    *(f32x4*)(out + (size_t)r1 * 128 + qlane * 8 + 4) = (accB + pB) * inv;
  }
#undef T1_CHUNK
}

extern "C" void kernel_launch(void* const* d_in, const int* in_sizes, int n_in,
                              void* d_out, int out_size, void* d_ws, size_t ws_size,
                              hipStream_t stream) {
  const float* hm  = (const float*)d_in[0];
  const float* adj = (const float*)d_in[1];
  const float* wgt = (const float*)d_in[2];
  const float* aw  = (const float*)d_in[3];
  float* out = (float*)d_out;

  char* ws = (char*)d_ws;
  __bf16* whR = (__bf16*)ws; ws += (size_t)GN * 128 * 2;   // 1.5 MB
  float* lp2  = (float*)ws;  ws += GN * GH * 4;            // 96 KB
  float* lc2  = (float*)ws;  ws += GN * GH * 4;            // 96 KB

  gat_wh<<<96, 256, 0, stream>>>(hm, wgt, aw, whR, lp2, lc2);
  gat_fused<<<GN / 4, 256, 0, stream>>>(adj, whR, lp2, lc2, out);
}

// Round 20
// 55.445 us; speedup vs baseline: 1.3832x; 1.3832x over previous
//
#include <hip/hip_runtime.h>
#include <hip/hip_bf16.h>
#include <stdint.h>
#include <stddef.h>

#define GN 6144
#define GH 4
#define HALF 3072
#define MAXD2 256  /* slots per HALF-row; deg/2 ~ 154 +/- 12 (8.5 sigma) */

typedef float    f32x2  __attribute__((ext_vector_type(2)));
typedef float    f32x4  __attribute__((ext_vector_type(4)));
typedef float    f32x16 __attribute__((ext_vector_type(16)));
typedef unsigned u32x4  __attribute__((ext_vector_type(4)));
typedef __bf16   bf16x4 __attribute__((ext_vector_type(4)));
typedef __bf16   bf16x8 __attribute__((ext_vector_type(8)));

__device__ __forceinline__ float fast_exp2(float x) {
#if __has_builtin(__builtin_amdgcn_exp2f)
  return __builtin_amdgcn_exp2f(x);
#else
  return exp2f(x);
#endif
}

// ---------------- K1: wh GEMM -> row-major bf16 whR + lp2/lc2 ------------
__global__ __launch_bounds__(256) void gat_wh(const float* __restrict__ hm,
                                              const float* __restrict__ wgt,
                                              const float* __restrict__ aw,
                                              __bf16* __restrict__ whR,
                                              float* __restrict__ lp2,
                                              float* __restrict__ lc2) {
  __shared__ float ldsC[64 * 132];
  const int t = threadIdx.x;
  const int wave = t >> 6, lane = t & 63;
  const int col = lane & 31, kg = lane >> 5;
  const int n0 = blockIdx.x * 64;
  const int rowHalf = (wave & 1) * 32;
  const int colBase = (wave >> 1) * 64;

  f32x16 acc[2];
#pragma unroll
  for (int ct = 0; ct < 2; ++ct)
#pragma unroll
    for (int i = 0; i < 16; ++i) acc[ct][i] = 0.0f;

#pragma unroll
  for (int kk = 0; kk < 8; ++kk) {
    const int k = kk * 16 + kg * 8;
    const f32x4 h0 = *(const f32x4*)(hm + (size_t)(n0 + rowHalf + col) * 128 + k);
    const f32x4 h1 = *(const f32x4*)(hm + (size_t)(n0 + rowHalf + col) * 128 + k + 4);
    bf16x8 af;
#pragma unroll
    for (int e = 0; e < 4; ++e) { af[e] = (__bf16)h0[e]; af[e + 4] = (__bf16)h1[e]; }
#pragma unroll
    for (int ct = 0; ct < 2; ++ct) {
      bf16x8 bfr;  // wgt column reads: coalesced across lanes
#pragma unroll
      for (int e = 0; e < 8; ++e)
        bfr[e] = (__bf16)wgt[(size_t)(k + e) * 128 + colBase + ct * 32 + col];
      acc[ct] = __builtin_amdgcn_mfma_f32_32x32x16_bf16(af, bfr, acc[ct], 0, 0, 0);
    }
  }
  // C layout (32x32): col = lane&31, row = (r&3) + 8*(r>>2) + 4*(lane>>5)
#pragma unroll
  for (int ct = 0; ct < 2; ++ct)
#pragma unroll
    for (int r = 0; r < 16; ++r)
      ldsC[(rowHalf + (r & 3) + 8 * (r >> 2) + 4 * kg) * 132 + colBase + ct * 32 + col] =
          acc[ct][r];
  __syncthreads();

  {  // ROW-MAJOR bf16 store: whR[n][f] (sparse PV gathers whole rows)
    const int rr = t >> 2, cg = (t & 3) * 32;
    __bf16* dst = whR + (size_t)(n0 + rr) * 128 + cg;
#pragma unroll
    for (int q = 0; q < 4; ++q) {
      bf16x8 v;
#pragma unroll
      for (int e = 0; e < 8; ++e) v[e] = (__bf16)ldsC[rr * 132 + cg + q * 8 + e];
      *(bf16x8*)(dst + q * 8) = v;
    }
  }
  {  // lp/lc dots, pre-scaled by log2(e)
    const int nl = t & 63, h = t >> 6;
    float sp = 0.f, sd = 0.f;
#pragma unroll
    for (int f = 0; f < 32; ++f) {
      const float v = ldsC[nl * 132 + h * 32 + f];
      sp = fmaf(v, aw[h * 64 + f], sp);
      sd = fmaf(v, aw[h * 64 + 32 + f], sd);
    }
    const float LOG2E = 1.4426950408889634f;
    lp2[(n0 + nl) * GH + h] = sp * LOG2E;
    lc2[(n0 + nl) * GH + h] = sd * LOG2E;
  }
}

// ---------------- K2: FUSED compact + softmax + PV -----------------------
// R18 (best known: 55.6us). R19's cross-task interleave REGRESSED (76.7us:
// TLP halved, 49K bank conflicts, ballot sync points inside PV) — reverted.
// Structure: (1) phase-1 adj ballot-compact with depth-4 prefetch;
// (2) e-phase for ALL chunks (els bf16, 8KB/block); (3) ONE long widened-PV
// loop — lane owns 8 feats (dwordx4=16B), 16 lanes/row, 4 edges/instr.
__global__ __launch_bounds__(256) void gat_fused(const float* __restrict__ adj,
                                                 const __bf16* __restrict__ whR,
                                                 const float* __restrict__ lp2,
                                                 const float* __restrict__ lc2,
                                                 float* __restrict__ out) {
  __shared__ unsigned short jidx[4][MAXD2];  // 2 KB: compacted edge columns
  __shared__ __bf16 elsb[4][MAXD2 * GH];     // 8 KB: e (bf16) for ALL edges
  __shared__ float accx[4][16][8];           // 2 KB: cross-wave acc exchange
  __shared__ float denx[4][4];               // 64 B: per-wave head denoms
  const int t = threadIdx.x, wave = t >> 6, lane = t & 63;
  const int row = blockIdx.x * 2 + (wave >> 1);
  const int half = wave & 1;
  const float* arow = adj + (size_t)row * GN + half * HALF;

  // ---- phase 1: ballot-compact, adj prefetch depth 4 ----
  unsigned base = 0;
  f32x4 buf[4];
#pragma unroll
  for (int c = 0; c < 4; ++c) buf[c] = *(const f32x4*)(arow + c * 256 + lane * 4);
#pragma unroll 4
  for (int c = 0; c < 12; ++c) {      // 12 chunks x 256 j; c&3 static
    const f32x4 a = buf[c & 3];
    if (c + 4 < 12) buf[c & 3] = *(const f32x4*)(arow + (c + 4) * 256 + lane * 4);
#pragma unroll
    for (int s = 0; s < 4; ++s) {
      const bool p = a[s] > 0.f;
      const unsigned long long m = __ballot(p);
      const unsigned rank = (unsigned)__popcll(m & ((1ull << lane) - 1ull));
      const unsigned pos = base + rank;
      if (p && pos < MAXD2)           // clamp: overflow drops edges, no UB
        jidx[wave][pos] = (unsigned short)(half * HALF + c * 256 + lane * 4 + s);
      base += (unsigned)__popcll(m);  // ballot is uniform -> scalar add
    }
  }
  int dg = (int)base;                 // wave-uniform degree (this half)
  if (dg > MAXD2) dg = MAXD2;
  // zero-pad tail: every slot phase 2 may touch must be a VALID row (R14)
  for (int k = dg + lane; k < MAXD2; k += 64) jidx[wave][k] = 0;
  // same-wave LDS RAW below: compiler inserts lgkmcnt waits; no barrier.

  // ---- phase 2a: e-phase for ALL chunks (bf16 store; pads write e=0) ----
  const f32x4 lpv = *(const f32x4*)(lp2 + (size_t)row * GH);
  f32x2 d01 = f32x2{0.f, 0.f}, d23 = f32x2{0.f, 0.f};
  const int nch = (dg + 63) >> 6;
  for (int c = 0; c < nch; ++c) {
    const int k = c * 64 + lane;
    const bool valid = k < dg;
    const int jv = valid ? (int)jidx[wave][k] : 0;
    const f32x4 lc = *(const f32x4*)(lc2 + (size_t)jv * GH);

    f32x2 x01 = f32x2{lpv[0] + lc[0], lpv[1] + lc[1]};
    f32x2 x23 = f32x2{lpv[2] + lc[2], lpv[3] + lc[3]};
    x01 = __builtin_elementwise_max(x01, x01 * 0.2f);
    x23 = __builtin_elementwise_max(x23, x23 * 0.2f);
    const float vf = valid ? 1.f : 0.f;
    const f32x2 e01 = f32x2{fast_exp2(x01[0]), fast_exp2(x01[1])} * vf;
    const f32x2 e23 = f32x2{fast_exp2(x23[0]), fast_exp2(x23[1])} * vf;
    d01 += e01; d23 += e23;
    bf16x4 ep;
    ep[0] = (__bf16)e01[0]; ep[1] = (__bf16)e01[1];
    ep[2] = (__bf16)e23[0]; ep[3] = (__bf16)e23[1];
    *(bf16x4*)&elsb[wave][k * 4] = ep;
  }

  // ---- phase 2b: ONE long widened-PV loop over all edges ----
  const int qlane = lane & 15;         // feature group: feats qlane*8..+8
  const int elane = lane >> 4;         // edge slot within group of 4
  const int hsel = qlane >> 2;         // head of this lane's 8 feats
  f32x4 accA = f32x4{0.f, 0.f, 0.f, 0.f};
  f32x4 accB = f32x4{0.f, 0.f, 0.f, 0.f};

  const int ngrp = (dg + 3) >> 2;      // groups of 4 edges (<= 64)
#pragma unroll 4
  for (int g = 0; g < ngrp; ++g) {
    const int es = g * 4 + elane;                       // this lane's edge
    const int jj = (int)jidx[wave][es];                 // 16-lane broadcast
    const u32x4 wb = *(const u32x4*)(whR + (size_t)jj * 128 + qlane * 8);
    const float eb = (float)elsb[wave][es * 4 + hsel];  // padded edges: 0
#pragma unroll
    for (int w = 0; w < 4; ++w) {
      const float wlo = __uint_as_float(wb[w] << 16);
      const float whi = __uint_as_float(wb[w] & 0xffff0000u);
      if (w < 2) {
        accA[2 * w]     = fmaf(eb, wlo, accA[2 * w]);
        accA[2 * w + 1] = fmaf(eb, whi, accA[2 * w + 1]);
      } else {
        accB[2 * w - 4] = fmaf(eb, wlo, accB[2 * w - 4]);
        accB[2 * w - 3] = fmaf(eb, whi, accB[2 * w - 3]);
      }
    }
  }

  // fold edge-slot lanes: xor 16 (slot bit0), xor 32 (slot bit1)
#pragma unroll
  for (int off = 16; off <= 32; off <<= 1) {
#pragma unroll
    for (int e = 0; e < 4; ++e) {
      accA[e] += __shfl_xor(accA[e], off);
      accB[e] += __shfl_xor(accB[e], off);
    }
  }
  // in-wave denominator reduce (all 4 heads end up in every lane)
  f32x4 dv = f32x4{d01[0], d01[1], d23[0], d23[1]};
#pragma unroll
  for (int off = 1; off < 64; off <<= 1) {
    dv[0] += __shfl_xor(dv[0], off);
    dv[1] += __shfl_xor(dv[1], off);
    dv[2] += __shfl_xor(dv[2], off);
    dv[3] += __shfl_xor(dv[3], off);
  }

  // ---- cross-wave combine (the 2 halves of each row) ----
  if (lane < 16) {
    *(f32x4*)&accx[wave][qlane][0] = accA;
    *(f32x4*)&accx[wave][qlane][4] = accB;
  }
  if (lane == 0) *(f32x4*)&denx[wave][0] = dv;
  __syncthreads();
  if ((wave & 1) == 0 && lane < 16) {
    const f32x4 pA = *(const f32x4*)&accx[wave + 1][qlane][0];
    const f32x4 pB = *(const f32x4*)&accx[wave + 1][qlane][4];
    const float den = denx[wave][hsel] + denx[wave + 1][hsel];
    const float inv = 1.0f / den;
    *(f32x4*)(out + (size_t)row * 128 + qlane * 8)     = (accA + pA) * inv;
    *(f32x4*)(out + (size_t)row * 128 + qlane * 8 + 4) = (accB + pB) * inv;
  }
}

extern "C" void kernel_launch(void* const* d_in, const int* in_sizes, int n_in,
                              void* d_out, int out_size, void* d_ws, size_t ws_size,
                              hipStream_t stream) {
  const float* hm  = (const float*)d_in[0];
  const float* adj = (const float*)d_in[1];
  const float* wgt = (const float*)d_in[2];
  const float* aw  = (const float*)d_in[3];
  float* out = (float*)d_out;

  char* ws = (char*)d_ws;
  __bf16* whR = (__bf16*)ws; ws += (size_t)GN * 128 * 2;   // 1.5 MB
  float* lp2  = (float*)ws;  ws += GN * GH * 4;            // 96 KB
  float* lc2  = (float*)ws;  ws += GN * GH * 4;            // 96 KB

  gat_wh<<<96, 256, 0, stream>>>(hm, wgt, aw, whR, lp2, lc2);
  gat_fused<<<GN / 2, 256, 0, stream>>>(adj, whR, lp2, lc2, out);
}